// Round 8
// baseline (652.132 us; speedup 1.0000x reference)
//
#include <hip/hip_runtime.h>

#define D_ 1024
#define S_ 2048
#define B_ 32
#define BM 128
#define BN 256
#define BK 64
#define NKT 32  // K tiles: 16 from W/k + 16 from U/q (BK=64)

typedef __attribute__((ext_vector_type(8))) _Float16 f16x8;  // 4 VGPR MFMA operand
typedef __attribute__((ext_vector_type(16))) float f32x16;   // MFMA 32x32 acc

// async global->LDS, 16B per lane. LDS dest is wave-uniform base + lane*16;
// our per-lane pointers are linear in lane, so this matches exactly.
__device__ __forceinline__ void async_ld16(const void* g, void* l) {
  __builtin_amdgcn_global_load_lds(
      (const __attribute__((address_space(1))) void*)g,
      (__attribute__((address_space(3))) void*)l, 16, 0, 0);
}

// ---------------------------------------------------------------------------
// prep: round W,U to single f16 plane, stored in FRAGMENT ORDER per 128x64
// tile (1024 granules of 8 f16) — layout identical to R5/R7 (verified):
//   granule = ((ks*4 + wr*2 + fm) << 6) | (lhi << 5) | l31
//   row     = wr*64 + fm*32 + l31      (d within tile)
//   chunk   = ks*2 + lhi               (8-elem k-group within 64)
// ---------------------------------------------------------------------------
__global__ void prep_kernel(const float* __restrict__ W, const float* __restrict__ U,
                            _Float16* __restrict__ wf, _Float16* __restrict__ uf) {
  int t = blockIdx.x * blockDim.x + threadIdx.x;  // [0, 131072) granules
  const float* src = blockIdx.y ? U : W;
  _Float16* dst = blockIdx.y ? uf : wf;

  int tile = t >> 10;       // [0,128) = mt*16 + kt
  int g    = t & 1023;      // granule within tile
  int top  = g >> 6;        // [0,16)
  int ks = top >> 2, wr = (top >> 1) & 1, fm = top & 1;
  int lhi = (g >> 5) & 1, l31 = g & 31;
  int row   = wr * 64 + fm * 32 + l31;
  int chunk = ks * 2 + lhi;
  int mt = tile >> 4, kt = tile & 15;
  int d = mt * 128 + row;
  int e = kt * 64 + chunk * 8;

  const float* p = src + (size_t)d * D_ + e;
  f16x8 hv;
#pragma unroll
  for (int j = 0; j < 8; ++j) hv[j] = (_Float16)p[j];  // RN
  *(f16x8*)(dst + (size_t)t * 8) = hv;                 // linear, coalesced
}

// ---------------------------------------------------------------------------
// gemm v8: T3-minimal single-barrier pipeline. 128x256 tile, 8 waves (2x4),
// BK=64, 1-pass f16, BOTH A and B double-buffered (96KB LDS, 1 block/CU).
// Per kt: issue A(kt+1) gll -> Af[nxt]; issue B(kt+1) -> regs; compute kt
// from [cur]; cvt+ds_write B(kt+1) -> Bf[nxt]; ONE __syncthreads.
// All vmem is consumed by register deps before the barrier, so the barrier's
// vmcnt(0) is naturally free: loads get a full iteration of latency cover.
// ---------------------------------------------------------------------------
__global__ void __launch_bounds__(512, 2)
gemm_kernel(const float* __restrict__ kten, const float* __restrict__ qten,
            const float* __restrict__ v,
            const _Float16* __restrict__ wf, const _Float16* __restrict__ uf,
            float* __restrict__ partials) {
  __shared__ __align__(16) _Float16 Af[2][BM * BK];  // 2 x 16 KB
  __shared__ __align__(16) _Float16 Bf[2][BN * BK];  // 2 x 32 KB
  __shared__ float vbuf[BM];
  __shared__ float red[2][BN];

  const int tid  = threadIdx.x;
  const int lane = tid & 63;
  const int wid  = tid >> 6;        // [0,8)
  const int wr   = wid >> 2;        // [0,2) d-half
  const int wc   = wid & 3;         // [0,4) s-quarter

  // Block decode: 2048 blocks = 256 groups x 8 dblk. The 8 d-siblings of a
  // (b, s-tile) group share bid&7 -> same XCD -> k/q tiles served from L2.
  int bid  = blockIdx.x;
  int g    = ((bid >> 6) << 3) | (bid & 7);  // [0,256)
  int dblk = (bid >> 3) & 7;
  int st   = g & 7;
  int b    = g >> 3;
  int s0   = st * BN;

  if (tid < BM) vbuf[tid] = v[(size_t)b * D_ + dblk * BM + tid];

  f32x16 acc[2][2];
#pragma unroll
  for (int i = 0; i < 2; ++i)
#pragma unroll
    for (int j = 0; j < 2; ++j)
#pragma unroll
      for (int r = 0; r < 16; ++r) acc[i][j][r] = 0.0f;

  const int nB = tid & 255;  // B-stage column within s-tile
  const int kq = tid >> 8;   // 0/1: which 32 of the 64 k-rows this thread loads

  // --- staging helpers -----------------------------------------------------
  // A: exactly 1024 granules = 16KB tile (512 threads x 2 gll ops). Issued
  // FIRST so it is older than the B loads; the B cvt's vmcnt wait covers it.
  auto issueA = [&](int kt, int buf) {
    const int half = kt >> 4, ktt = kt & 15;
    const _Float16* at = (half ? uf : wf) + (size_t)(dblk * 16 + ktt) * 8192;
#pragma unroll
    for (int i = 0; i < 2; ++i)
      async_ld16(at + (size_t)(tid + i * 512) * 8, &Af[buf][(size_t)(tid + i * 512) * 8]);
  };
  auto loadB = [&](int kt, float* xv) {
    const int half = kt >> 4, ktt = kt & 15;
    const float* xb = (half ? qten : kten) + (size_t)b * (D_ * S_) + (size_t)(ktt * 64) * S_ + s0;
    const float* col = xb + nB + (size_t)(kq * 32) * S_;
#pragma unroll
    for (int j = 0; j < 32; ++j) xv[j] = col[(size_t)j * S_];
  };
  auto writeB = [&](const float* xv, int buf) {
#pragma unroll
    for (int cl = 0; cl < 4; ++cl) {          // chunk-local: 4 chunks of 8 rows
      f16x8 hv;
#pragma unroll
      for (int w = 0; w < 8; ++w) hv[w] = (_Float16)xv[cl * 8 + w];
      int c   = kq * 4 + cl;                  // chunk in [0,8)
      int cks = c >> 1, clh = c & 1;
      // granule = ((ks*8 + wc_n*2 + fn_n) << 6) | (lhi<<5) | l31
      int gnl = (((cks * 8 + (nB >> 6) * 2 + ((nB >> 5) & 1)) << 6) | (clh << 5) | (nB & 31));
      *(f16x8*)&Bf[buf][(size_t)gnl * 8] = hv;
    }
  };

  // --- prologue: stage kt=0 into buf 0 --------------------------------------
  float xv[32];
  issueA(0, 0);
  loadB(0, xv);
  writeB(xv, 0);       // cvt waits its loads (vmcnt covers gll A too: older)
  __syncthreads();     // publishes Af[0] (gll) + Bf[0]; vmcnt already 0

  int cur = 0;
  for (int kt = 0; kt < NKT; ++kt) {
    const int nxt = cur ^ 1;
    const bool pre = (kt + 1 < NKT);

    // ---- issue next-tile loads; a FULL iteration of latency cover ----
    if (pre) {
      issueA(kt + 1, nxt);   // gll -> Af[nxt] (disjoint from Af[cur])
      loadB(kt + 1, xv);     // 32 coalesced f32 -> regs
    }

    // ---- compute current: 4 k-steps x 2x2 frags = 16 MFMA / wave ----
#pragma unroll
    for (int ks = 0; ks < 4; ++ks) {
      f16x8 af[2], bf[2];
#pragma unroll
      for (int fm = 0; fm < 2; ++fm) {
        int gA = ((ks * 4 + wr * 2 + fm) << 6) + lane;  // contiguous per wave
        af[fm] = *(const f16x8*)&Af[cur][(size_t)gA * 8];
      }
#pragma unroll
      for (int fn = 0; fn < 2; ++fn) {
        int gB = ((ks * 8 + wc * 2 + fn) << 6) + lane;
        bf[fn] = *(const f16x8*)&Bf[cur][(size_t)gB * 8];
      }
#pragma unroll
      for (int fm = 0; fm < 2; ++fm)
#pragma unroll
        for (int fn = 0; fn < 2; ++fn)
          acc[fm][fn] = __builtin_amdgcn_mfma_f32_32x32x16_f16(af[fm], bf[fn], acc[fm][fn], 0, 0, 0);
    }

    // ---- cvt + write B(kt+1) into Bf[nxt]; reg dep waits the B loads,
    //      which by now had the whole compute phase to land ----
    if (pre) writeB(xv, nxt);

    __syncthreads();   // ONE barrier/kt: publishes Af[nxt]+Bf[nxt].
                       // vmcnt is already 0 (all vmem consumed) -> no drain.
    cur = nxt;
  }

  // ---- epilogue: tanh, weight by v[d], column-reduce the 128 d-rows ----
  float psum[2] = {0.f, 0.f};
#pragma unroll
  for (int fm = 0; fm < 2; ++fm)
#pragma unroll
    for (int fn = 0; fn < 2; ++fn)
#pragma unroll
      for (int r = 0; r < 16; ++r) {
        // C/D layout: col = lane&31, row = (r&3)+8*(r>>2)+4*(lane>>5)
        int row = wr * 64 + fm * 32 + (r & 3) + 8 * (r >> 2) + 4 * (lane >> 5);
        float x  = acc[fm][fn][r];
        float th = 1.0f - 2.0f / (__expf(2.0f * x) + 1.0f);  // tanh(x)
        psum[fn] += vbuf[row] * th;
      }
#pragma unroll
  for (int fn = 0; fn < 2; ++fn) psum[fn] += __shfl_xor(psum[fn], 32);
  if (lane < 32) {
    red[wr][wc * 64 + lane]      = psum[0];
    red[wr][wc * 64 + 32 + lane] = psum[1];
  }
  __syncthreads();
  if (tid < BN) {
    float val = red[0][tid] + red[1][tid];
    partials[(size_t)(dblk * B_ + b) * S_ + s0 + tid] = val;
  }
}

// ---------------------------------------------------------------------------
// softmax over S per batch; sums the 8 d-block partials first. Deterministic.
// ---------------------------------------------------------------------------
__global__ void softmax_kernel(const float* __restrict__ partials, float* __restrict__ out) {
  __shared__ float logit[S_];
  __shared__ float wred[2][4];
  int b = blockIdx.x, tid = threadIdx.x;
  int lane = tid & 63, wid = tid >> 6;
  float lmax = -1e30f;
  for (int i = tid; i < S_; i += 256) {
    float acc = 0.f;
#pragma unroll
    for (int d = 0; d < 8; ++d) acc += partials[(size_t)(d * B_ + b) * S_ + i];
    logit[i] = acc;
    lmax = fmaxf(lmax, acc);
  }
#pragma unroll
  for (int o = 32; o; o >>= 1) lmax = fmaxf(lmax, __shfl_xor(lmax, o));
  if (lane == 0) wred[0][wid] = lmax;
  __syncthreads();
  float m = fmaxf(fmaxf(wred[0][0], wred[0][1]), fmaxf(wred[0][2], wred[0][3]));
  float lsum = 0.f;
  for (int i = tid; i < S_; i += 256) {
    float ex = __expf(logit[i] - m);
    logit[i] = ex;
    lsum += ex;
  }
#pragma unroll
  for (int o = 32; o; o >>= 1) lsum += __shfl_xor(lsum, o);
  if (lane == 0) wred[1][wid] = lsum;
  __syncthreads();
  float tot = wred[1][0] + wred[1][1] + wred[1][2] + wred[1][3];
  float inv = 1.0f / tot;
  for (int i = tid; i < S_; i += 256) out[(size_t)b * S_ + i] = logit[i] * inv;
}

extern "C" void kernel_launch(void* const* d_in, const int* in_sizes, int n_in,
                              void* d_out, int out_size, void* d_ws, size_t ws_size,
                              hipStream_t stream) {
  const float* q = (const float*)d_in[0];
  const float* k = (const float*)d_in[1];
  const float* v = (const float*)d_in[2];
  const float* W = (const float*)d_in[3];
  const float* U = (const float*)d_in[4];

  // ws layout: 2x f16[1024*1024] (4 MB) + partials f32[8][32][2048] (2 MB)
  _Float16* wf = (_Float16*)d_ws;
  _Float16* uf = wf + (size_t)D_ * D_;
  float* partials = (float*)(uf + (size_t)D_ * D_);

  prep_kernel<<<dim3(512, 2), 256, 0, stream>>>(W, U, wf, uf);
  gemm_kernel<<<dim3(2048), 512, 0, stream>>>(k, q, v, wf, uf, partials);
  softmax_kernel<<<dim3(B_), 256, 0, stream>>>(partials, (float*)d_out);
}

// Round 9
// 460.672 us; speedup vs baseline: 1.4156x; 1.4156x over previous
//
#include <hip/hip_runtime.h>

#define D_ 1024
#define S_ 2048
#define B_ 32
#define BM 256
#define BN 256
#define BK 64
#define NKT 32  // K tiles: 16 from W/k + 16 from U/q (BK=64)

typedef __attribute__((ext_vector_type(8))) _Float16 f16x8;  // 4 VGPR MFMA operand
typedef __attribute__((ext_vector_type(16))) float f32x16;   // MFMA 32x32 acc

// async global->LDS, 16B per lane; LDS dest = wave-uniform base + lane*16.
__device__ __forceinline__ void async_ld16(const void* g, void* l) {
  __builtin_amdgcn_global_load_lds(
      (const __attribute__((address_space(1))) void*)g,
      (__attribute__((address_space(3))) void*)l, 16, 0, 0);
}

// ---------------------------------------------------------------------------
// prep: W,U -> f16, FRAGMENT ORDER per 256x64 A-tile (2048 granules of 8):
//   granule = ((ks*8 + wr*4 + fm) << 6) | lane
//   row     = wr*128 + fm*32 + (lane&31)   (d within tile)
//   chunk   = ks*2 + (lane>>5)             (8-elem e-group within 64)
// => GEMM A-stage is a linear 32KB gll copy; every fragment ds_read_b128 is
//    64 lanes x 16B contiguous: zero bank conflicts (verified pattern R2-R8).
// ---------------------------------------------------------------------------
__global__ void prep_kernel(const float* __restrict__ W, const float* __restrict__ U,
                            _Float16* __restrict__ wf, _Float16* __restrict__ uf) {
  int t = blockIdx.x * blockDim.x + threadIdx.x;  // [0, 131072) granules
  const float* src = blockIdx.y ? U : W;
  _Float16* dst = blockIdx.y ? uf : wf;

  int tile = t >> 11;        // [0,64) = dblk*16 + ktt
  int g    = t & 2047;
  int top  = g >> 6;         // [0,32) = ks*8 + wr*4 + fm
  int ks = top >> 3, wr = (top >> 2) & 1, fm = top & 3;
  int lane = g & 63, l31 = lane & 31, lhi = lane >> 5;
  int row   = wr * 128 + fm * 32 + l31;
  int chunk = ks * 2 + lhi;
  int d = (tile >> 4) * 256 + row;
  int e = (tile & 15) * 64 + chunk * 8;

  const float* p = src + (size_t)d * D_ + e;
  f16x8 hv;
#pragma unroll
  for (int j = 0; j < 8; ++j) hv[j] = (_Float16)p[j];  // RN
  *(f16x8*)(dst + (size_t)t * 8) = hv;                 // linear, coalesced
}

// ---------------------------------------------------------------------------
// gemm v9: 256x256 tile, BK=64, 8 waves (2Mx4N), wave-tile 128x64 (4fm x 2fn),
// 4 phases/K-tile with raw s_barrier between phases, ONE __syncthreads/K-tile.
// Per phase ks: {staging slice for kt+1} + {6 ds_read frags} + setprio(1) +
// 8 MFMA + setprio(0). Staging: ph0: 2 gll A + B loads j0-15; ph1: 2 gll A +
// B loads j16-31; ph2: cvt+write B half0; ph3: cvt+write B half1.
// B cvt's compiler wait is COUNTED (younger A-gll stay in flight); the only
// vmcnt(0) drain is the kt-boundary __syncthreads covering well-aged A-gll.
// Intra-kt barriers: reads cur / writes nxt are disjoint -> hazard-free.
// LDS 128KB+3KB -> 1 block/CU (8 waves).
// ---------------------------------------------------------------------------
__global__ void __launch_bounds__(512, 2)
gemm_kernel(const float* __restrict__ kten, const float* __restrict__ qten,
            const float* __restrict__ v,
            const _Float16* __restrict__ wf, const _Float16* __restrict__ uf,
            float* __restrict__ partials) {
  __shared__ __align__(16) _Float16 Af[2][BM * BK];  // 2 x 32 KB
  __shared__ __align__(16) _Float16 Bf[2][BN * BK];  // 2 x 32 KB
  __shared__ float vbuf[BM];
  __shared__ float red[2][BN];

  const int tid  = threadIdx.x;
  const int lane = tid & 63;
  const int wid  = tid >> 6;        // [0,8)
  const int wr   = wid >> 2;        // [0,2) d-half (128 rows)
  const int wc   = wid & 3;         // [0,4) s-quarter (64 cols)

  // Block decode: 1024 blocks = 256 groups x 4 dblk; the 4 d-siblings of a
  // (b, s-tile) group share bid&7 -> same XCD -> k/q tiles served from L2.
  int bid  = blockIdx.x;
  int g    = ((bid >> 5) << 3) | (bid & 7);  // [0,256)
  int dblk = (bid >> 3) & 3;
  int st   = g & 7;
  int b    = g >> 3;
  int s0   = st * BN;

  if (tid < BM) vbuf[tid] = v[(size_t)b * D_ + dblk * BM + tid];

  f32x16 acc[4][2];
#pragma unroll
  for (int i = 0; i < 4; ++i)
#pragma unroll
    for (int j = 0; j < 2; ++j)
#pragma unroll
      for (int r = 0; r < 16; ++r) acc[i][j][r] = 0.0f;

  const int nB = tid & 255;  // B column (s) this thread stages
  const int kq = tid >> 8;   // 0/1: e-rows [kq*32, kq*32+32)

  // cvt + fragment-order LDS write of one 16-element half (chunks 2h, 2h+1).
  auto writeBhalf = [&](const float* xv, int h, int buf) {
#pragma unroll
    for (int cl = 2 * h; cl < 2 * h + 2; ++cl) {
      f16x8 hv;
#pragma unroll
      for (int w = 0; w < 8; ++w) hv[w] = (_Float16)xv[cl * 8 + w];
      int c = kq * 4 + cl, cks = c >> 1, clh = c & 1;
      int gnl = ((cks * 8 + (nB >> 6) * 2 + ((nB >> 5) & 1)) << 6) | (clh << 5) | (nB & 31);
      *(f16x8*)&Bf[buf][(size_t)gnl * 8] = hv;
    }
  };

  // --- prologue: stage kt=0 into buf 0 (full drain once) --------------------
  float xv[32];
  {
    const _Float16* at0 = wf + (size_t)(dblk * 16) * 16384;
#pragma unroll
    for (int i = 0; i < 4; ++i)  // exactly 2048 granules = 32KB (audited)
      async_ld16(at0 + (size_t)(tid + i * 512) * 8, &Af[0][(size_t)(tid + i * 512) * 8]);
    const float* col = kten + (size_t)b * (D_ * S_) + s0 + nB + (size_t)(kq * 32) * S_;
#pragma unroll
    for (int j = 0; j < 32; ++j) xv[j] = col[(size_t)j * S_];
    writeBhalf(xv, 0, 0);
    writeBhalf(xv, 1, 0);
  }
  __syncthreads();

  int cur = 0;
  for (int kt = 0; kt < NKT; ++kt) {
    const int nxt = cur ^ 1;
    const int ktn = (kt + 1 < NKT) ? kt + 1 : kt;  // clamped: last iter redundant
    const int halfn = ktn >> 4, kttn = ktn & 15;
    const _Float16* at_n = (halfn ? uf : wf) + (size_t)(dblk * 16 + kttn) * 16384;
    const float* coln = (halfn ? qten : kten) + (size_t)b * (D_ * S_)
                        + (size_t)(kttn * 64) * S_ + s0 + nB + (size_t)(kq * 32) * S_;

#pragma unroll
    for (int ks = 0; ks < 4; ++ks) {
      // ---- staging slice for kt+1 (issued before compute of this phase) ----
      if (ks == 0) {
        async_ld16(at_n + (size_t)tid * 8,         &Af[nxt][(size_t)tid * 8]);
        async_ld16(at_n + (size_t)(tid + 512) * 8, &Af[nxt][(size_t)(tid + 512) * 8]);
#pragma unroll
        for (int j = 0; j < 16; ++j) xv[j] = coln[(size_t)j * S_];
      } else if (ks == 1) {
        async_ld16(at_n + (size_t)(tid + 1024) * 8, &Af[nxt][(size_t)(tid + 1024) * 8]);
        async_ld16(at_n + (size_t)(tid + 1536) * 8, &Af[nxt][(size_t)(tid + 1536) * 8]);
#pragma unroll
        for (int j = 16; j < 32; ++j) xv[j] = coln[(size_t)j * S_];
      } else if (ks == 2) {
        writeBhalf(xv, 0, nxt);   // counted wait: A-gll stay in flight
      } else {
        writeBhalf(xv, 1, nxt);
      }

      // ---- compute phase ks: 6 ds_read_b128 + 8 MFMA ----
      f16x8 af[4], bf[2];
#pragma unroll
      for (int fm = 0; fm < 4; ++fm) {
        int gA = ((ks * 8 + wr * 4 + fm) << 6) + lane;  // contiguous per wave
        af[fm] = *(const f16x8*)&Af[cur][(size_t)gA * 8];
      }
#pragma unroll
      for (int fn = 0; fn < 2; ++fn) {
        int gB = ((ks * 8 + wc * 2 + fn) << 6) + lane;
        bf[fn] = *(const f16x8*)&Bf[cur][(size_t)gB * 8];
      }
      __builtin_amdgcn_s_setprio(1);
#pragma unroll
      for (int fm = 0; fm < 4; ++fm)
#pragma unroll
        for (int fn = 0; fn < 2; ++fn)
          acc[fm][fn] = __builtin_amdgcn_mfma_f32_32x32x16_f16(af[fm], bf[fn], acc[fm][fn], 0, 0, 0);
      __builtin_amdgcn_s_setprio(0);
      if (ks < 3) __builtin_amdgcn_s_barrier();  // phase-lock; no hazard (disjoint bufs)
    }
    __syncthreads();  // kt boundary: full drain (A-gll aged 2-4 phases) + flip
    cur = nxt;
  }

  // ---- epilogue: tanh, weight by v[d], column-reduce the 256 d-rows ----
  float psum[2] = {0.f, 0.f};
#pragma unroll
  for (int fm = 0; fm < 4; ++fm)
#pragma unroll
    for (int fn = 0; fn < 2; ++fn)
#pragma unroll
      for (int r = 0; r < 16; ++r) {
        // C/D layout: col = lane&31, row = (r&3)+8*(r>>2)+4*(lane>>5)
        int row = wr * 128 + fm * 32 + (r & 3) + 8 * (r >> 2) + 4 * (lane >> 5);
        float x  = acc[fm][fn][r];
        float th = 1.0f - 2.0f / (__expf(2.0f * x) + 1.0f);  // tanh(x)
        psum[fn] += vbuf[row] * th;
      }
#pragma unroll
  for (int fn = 0; fn < 2; ++fn) psum[fn] += __shfl_xor(psum[fn], 32);
  if (lane < 32) {
    red[wr][wc * 64 + lane]      = psum[0];
    red[wr][wc * 64 + 32 + lane] = psum[1];
  }
  __syncthreads();
  if (tid < BN) {
    float val = red[0][tid] + red[1][tid];
    partials[(size_t)(dblk * B_ + b) * S_ + s0 + tid] = val;
  }
}

// ---------------------------------------------------------------------------
// softmax over S per batch; sums the 4 d-block partials first. Deterministic.
// ---------------------------------------------------------------------------
__global__ void softmax_kernel(const float* __restrict__ partials, float* __restrict__ out) {
  __shared__ float logit[S_];
  __shared__ float wred[2][4];
  int b = blockIdx.x, tid = threadIdx.x;
  int lane = tid & 63, wid = tid >> 6;
  float lmax = -1e30f;
  for (int i = tid; i < S_; i += 256) {
    float acc = 0.f;
#pragma unroll
    for (int d = 0; d < 4; ++d) acc += partials[(size_t)(d * B_ + b) * S_ + i];
    logit[i] = acc;
    lmax = fmaxf(lmax, acc);
  }
#pragma unroll
  for (int o = 32; o; o >>= 1) lmax = fmaxf(lmax, __shfl_xor(lmax, o));
  if (lane == 0) wred[0][wid] = lmax;
  __syncthreads();
  float m = fmaxf(fmaxf(wred[0][0], wred[0][1]), fmaxf(wred[0][2], wred[0][3]));
  float lsum = 0.f;
  for (int i = tid; i < S_; i += 256) {
    float ex = __expf(logit[i] - m);
    logit[i] = ex;
    lsum += ex;
  }
#pragma unroll
  for (int o = 32; o; o >>= 1) lsum += __shfl_xor(lsum, o);
  if (lane == 0) wred[1][wid] = lsum;
  __syncthreads();
  float tot = wred[1][0] + wred[1][1] + wred[1][2] + wred[1][3];
  float inv = 1.0f / tot;
  for (int i = tid; i < S_; i += 256) out[(size_t)b * S_ + i] = logit[i] * inv;
}

extern "C" void kernel_launch(void* const* d_in, const int* in_sizes, int n_in,
                              void* d_out, int out_size, void* d_ws, size_t ws_size,
                              hipStream_t stream) {
  const float* q = (const float*)d_in[0];
  const float* k = (const float*)d_in[1];
  const float* v = (const float*)d_in[2];
  const float* W = (const float*)d_in[3];
  const float* U = (const float*)d_in[4];

  // ws layout: 2x f16[1024*1024] (4 MB) + partials f32[4][32][2048] (1 MB)
  _Float16* wf = (_Float16*)d_ws;
  _Float16* uf = wf + (size_t)D_ * D_;
  float* partials = (float*)(uf + (size_t)D_ * D_);

  prep_kernel<<<dim3(512, 2), 256, 0, stream>>>(W, U, wf, uf);
  gemm_kernel<<<dim3(1024), 512, 0, stream>>>(k, q, v, wf, uf, partials);
  softmax_kernel<<<dim3(B_), 256, 0, stream>>>(partials, (float*)d_out);
}

// Round 10
// 401.302 us; speedup vs baseline: 1.6250x; 1.1479x over previous
//
#include <hip/hip_runtime.h>

#define D_ 1024
#define S_ 2048
#define B_ 32
#define BM 256
#define BN 256
#define BK 64
#define NKT 32  // K tiles: 16 from W/k + 16 from U/q (BK=64)

typedef __attribute__((ext_vector_type(8))) _Float16 f16x8;  // 4 VGPR MFMA operand
typedef __attribute__((ext_vector_type(16))) float f32x16;   // MFMA 32x32 acc

// async global->LDS, 16B per lane; LDS dest = wave-uniform base + lane*16.
__device__ __forceinline__ void async_ld16(const void* g, void* l) {
  __builtin_amdgcn_global_load_lds(
      (const __attribute__((address_space(1))) void*)g,
      (__attribute__((address_space(3))) void*)l, 16, 0, 0);
}

// ---------------------------------------------------------------------------
// prep: W,U -> f16, FRAGMENT ORDER per 256x64 A-tile (2048 granules of 8):
//   granule = ((ks*8 + wr*4 + fm) << 6) | lane
//   row     = wr*128 + fm*32 + (lane&31)   (d within tile)
//   chunk   = ks*2 + (lane>>5)             (8-elem e-group within 64)
// Verified R9 (passed, absmax 3.9e-3). Zero-conflict fragment reads.
// ---------------------------------------------------------------------------
__global__ void prep_kernel(const float* __restrict__ W, const float* __restrict__ U,
                            _Float16* __restrict__ wf, _Float16* __restrict__ uf) {
  int t = blockIdx.x * blockDim.x + threadIdx.x;  // [0, 131072) granules
  const float* src = blockIdx.y ? U : W;
  _Float16* dst = blockIdx.y ? uf : wf;

  int tile = t >> 11;        // [0,64) = dblk*16 + ktt
  int g    = t & 2047;
  int top  = g >> 6;         // [0,32) = ks*8 + wr*4 + fm
  int ks = top >> 3, wr = (top >> 2) & 1, fm = top & 3;
  int lane = g & 63, l31 = lane & 31, lhi = lane >> 5;
  int row   = wr * 128 + fm * 32 + l31;
  int chunk = ks * 2 + lhi;
  int d = (tile >> 4) * 256 + row;
  int e = (tile & 15) * 64 + chunk * 8;

  const float* p = src + (size_t)d * D_ + e;
  f16x8 hv;
#pragma unroll
  for (int j = 0; j < 8; ++j) hv[j] = (_Float16)p[j];  // RN
  *(f16x8*)(dst + (size_t)t * 8) = hv;                 // linear, coalesced
}

// ---------------------------------------------------------------------------
// gemm v10: R9 geometry (256x256, BK=64, 8 waves 2Mx4N, wave-tile 128x64)
// with TRUE counted-vmcnt phase schedule (T3+T4+T5):
//  per kt (4 phases, fences pin program order = issue order):
//   ph0: gllA(kt+1) x2          | ds_read ks0 | setprio(1) 8 MFMA setprio(0) | s_barrier
//   ph1: gllA(kt+1) x2          | ks1 ...                                    | s_barrier
//   ph2: loadB(kt+2) j0-15->xvN | ks2 ...                                    | s_barrier
//   ph3: loadB(kt+2) j16-31     | cvt xvC->Bf[nxt] | ks3 ...
//   boundary: s_waitcnt vmcnt(32) lgkmcnt(0); s_barrier; sched_barrier(0)
//  VMEM order per kt = [gll x4 oldest][B x32 youngest]: vmcnt(32) retires the
//  gll, leaves all 32 B-loads in flight ACROSS the barrier (never drain to 0).
//  B is distance-2 prefetched into alternating reg banks xvA/xvB (static).
// ---------------------------------------------------------------------------
__global__ void __launch_bounds__(512, 2)
gemm_kernel(const float* __restrict__ kten, const float* __restrict__ qten,
            const float* __restrict__ v,
            const _Float16* __restrict__ wf, const _Float16* __restrict__ uf,
            float* __restrict__ partials) {
  __shared__ __align__(16) _Float16 Af[2][BM * BK];  // 2 x 32 KB
  __shared__ __align__(16) _Float16 Bf[2][BN * BK];  // 2 x 32 KB
  __shared__ float vbuf[BM];
  __shared__ float red[2][BN];

  const int tid  = threadIdx.x;
  const int lane = tid & 63;
  const int wid  = tid >> 6;        // [0,8)
  const int wr   = wid >> 2;        // [0,2) d-half (128 rows)
  const int wc   = wid & 3;         // [0,4) s-quarter (64 cols)

  int bid  = blockIdx.x;
  int g    = ((bid >> 5) << 3) | (bid & 7);  // [0,256): 4 dblk siblings same XCD
  int dblk = (bid >> 3) & 3;
  int st   = g & 7;
  int b    = g >> 3;
  int s0   = st * BN;

  if (tid < BM) vbuf[tid] = v[(size_t)b * D_ + dblk * BM + tid];

  f32x16 acc[4][2];
#pragma unroll
  for (int i = 0; i < 4; ++i)
#pragma unroll
    for (int j = 0; j < 2; ++j)
#pragma unroll
      for (int r = 0; r < 16; ++r) acc[i][j][r] = 0.0f;

  const int nB = tid & 255;  // B column (s) this thread stages
  const int kq = tid >> 8;   // 0/1: e-rows [kq*32, kq*32+32)

#define PH_FENCE asm volatile("" ::: "memory")
#define PH_BAR __builtin_amdgcn_s_barrier()

// 2 gll (1KB each) per part; parts 0,1 cover exactly 2048 granules = 32KB.
#define GLLA(ktn, buf, part) do {                                              \
    const int half_ = (ktn) >> 4, ktt_ = (ktn) & 15;                           \
    const _Float16* at_ = (half_ ? uf : wf) + (size_t)(dblk * 16 + ktt_) * 16384; \
    async_ld16(at_ + (size_t)(tid + (part) * 1024) * 8,                        \
               &Af[buf][(size_t)(tid + (part) * 1024) * 8]);                   \
    async_ld16(at_ + (size_t)(tid + (part) * 1024 + 512) * 8,                  \
               &Af[buf][(size_t)(tid + (part) * 1024 + 512) * 8]);             \
  } while (0)

// 16 coalesced strided f32 loads (rows kq*32 + [16h,16h+16)) into xv[16h..]
#define LOADB(ktn, xv, h) do {                                                 \
    const int half_ = (ktn) >> 4, ktt_ = (ktn) & 15;                           \
    const float* col_ = (half_ ? qten : kten) + (size_t)b * (D_ * S_)          \
                        + (size_t)(ktt_ * 64) * S_ + s0 + nB                   \
                        + (size_t)(kq * 32) * S_;                              \
    _Pragma("unroll")                                                          \
    for (int j = 16 * (h); j < 16 * (h) + 16; ++j) xv[j] = col_[(size_t)j * S_]; \
  } while (0)

// cvt 32 f32 -> 4 x f16x8, fragment-order ds_write (verified layout R9)
#define CVTWRITE(xv, buf) do {                                                 \
    _Pragma("unroll")                                                          \
    for (int cl = 0; cl < 4; ++cl) {                                           \
      f16x8 hv_;                                                               \
      _Pragma("unroll")                                                        \
      for (int w = 0; w < 8; ++w) hv_[w] = (_Float16)xv[cl * 8 + w];           \
      int c_ = kq * 4 + cl, cks_ = c_ >> 1, clh_ = c_ & 1;                     \
      int gnl_ = ((cks_ * 8 + (nB >> 6) * 2 + ((nB >> 5) & 1)) << 6)           \
                 | (clh_ << 5) | (nB & 31);                                    \
      *(f16x8*)&Bf[buf][(size_t)gnl_ * 8] = hv_;                               \
    }                                                                          \
  } while (0)

// 6 ds_read_b128 (contiguous per wave, zero conflicts) + 8 MFMA under setprio
#define COMPUTE_PHASE(cur_, ks_) do {                                          \
    f16x8 af_[4], bf_[2];                                                      \
    _Pragma("unroll")                                                          \
    for (int fm = 0; fm < 4; ++fm)                                             \
      af_[fm] = *(const f16x8*)&Af[cur_][(size_t)(((ks_) * 8 + wr * 4 + fm) * 64 + lane) * 8]; \
    _Pragma("unroll")                                                          \
    for (int fn = 0; fn < 2; ++fn)                                             \
      bf_[fn] = *(const f16x8*)&Bf[cur_][(size_t)(((ks_) * 8 + wc * 2 + fn) * 64 + lane) * 8]; \
    __builtin_amdgcn_s_setprio(1);                                             \
    _Pragma("unroll")                                                          \
    for (int fm = 0; fm < 4; ++fm)                                             \
      _Pragma("unroll")                                                        \
      for (int fn = 0; fn < 2; ++fn)                                           \
        acc[fm][fn] = __builtin_amdgcn_mfma_f32_32x32x16_f16(af_[fm], bf_[fn], acc[fm][fn], 0, 0, 0); \
    __builtin_amdgcn_s_setprio(0);                                             \
  } while (0)

// One K-tile: staging interleaved per phase; boundary leaves 32 B in flight.
#define STEP(kt_, cur_, xvC_, xvN_) do {                                       \
    const int nxt_ = (cur_) ^ 1;                                               \
    PH_FENCE; GLLA((kt_) + 1, nxt_, 0); COMPUTE_PHASE(cur_, 0); PH_BAR;        \
    PH_FENCE; GLLA((kt_) + 1, nxt_, 1); COMPUTE_PHASE(cur_, 1); PH_BAR;        \
    PH_FENCE; LOADB((kt_) + 2, xvN_, 0); COMPUTE_PHASE(cur_, 2); PH_BAR;       \
    PH_FENCE; LOADB((kt_) + 2, xvN_, 1); CVTWRITE(xvC_, nxt_);                 \
              COMPUTE_PHASE(cur_, 3);                                          \
    asm volatile("s_waitcnt vmcnt(32) lgkmcnt(0)" ::: "memory");               \
    PH_BAR;                                                                    \
    __builtin_amdgcn_sched_barrier(0);                                         \
  } while (0)

  // --- prologue: A(0)->Af[0]; B(0)->xvA->Bf[0]; B(1)->xvB; full drain once --
  float xvA[32], xvB[32];
  LOADB(0, xvA, 0); LOADB(0, xvA, 1);
  GLLA(0, 0, 0);    GLLA(0, 0, 1);
  LOADB(1, xvB, 0); LOADB(1, xvB, 1);
  CVTWRITE(xvA, 0);
  __syncthreads();

  // --- main loop: kt = 0..29, static xv parity via double-step --------------
  for (int it = 0; it < 15; ++it) {
    STEP(2 * it,     0, xvB, xvA);   // cvt B(kt+1)=xvB, load B(kt+2)->xvA
    STEP(2 * it + 1, 1, xvA, xvB);
  }

  // --- epilogue kt=30: stage gll(31) + cvt xvB=B(31); no more B loads -------
  PH_FENCE; GLLA(31, 1, 0); COMPUTE_PHASE(0, 0); PH_BAR;
  PH_FENCE; GLLA(31, 1, 1); COMPUTE_PHASE(0, 1); PH_BAR;
  PH_FENCE; COMPUTE_PHASE(0, 2); PH_BAR;
  PH_FENCE; CVTWRITE(xvB, 1); COMPUTE_PHASE(0, 3);
  __syncthreads();  // full drain: gll(31) + ds_writes published (once)
  // --- epilogue kt=31: pure compute from buffers [1] ------------------------
  COMPUTE_PHASE(1, 0); COMPUTE_PHASE(1, 1); COMPUTE_PHASE(1, 2); COMPUTE_PHASE(1, 3);

#undef STEP
#undef COMPUTE_PHASE
#undef CVTWRITE
#undef LOADB
#undef GLLA
#undef PH_BAR
#undef PH_FENCE

  // ---- epilogue: tanh, weight by v[d], column-reduce the 256 d-rows ----
  float psum[2] = {0.f, 0.f};
#pragma unroll
  for (int fm = 0; fm < 4; ++fm)
#pragma unroll
    for (int fn = 0; fn < 2; ++fn)
#pragma unroll
      for (int r = 0; r < 16; ++r) {
        // C/D layout: col = lane&31, row = (r&3)+8*(r>>2)+4*(lane>>5)
        int row = wr * 128 + fm * 32 + (r & 3) + 8 * (r >> 2) + 4 * (lane >> 5);
        float x  = acc[fm][fn][r];
        float th = 1.0f - 2.0f / (__expf(2.0f * x) + 1.0f);  // tanh(x)
        psum[fn] += vbuf[row] * th;
      }
#pragma unroll
  for (int fn = 0; fn < 2; ++fn) psum[fn] += __shfl_xor(psum[fn], 32);
  if (lane < 32) {
    red[wr][wc * 64 + lane]      = psum[0];
    red[wr][wc * 64 + 32 + lane] = psum[1];
  }
  __syncthreads();
  if (tid < BN) {
    float val = red[0][tid] + red[1][tid];
    partials[(size_t)(dblk * B_ + b) * S_ + s0 + tid] = val;
  }
}

// ---------------------------------------------------------------------------
// softmax over S per batch; sums the 4 d-block partials first. Deterministic.
// ---------------------------------------------------------------------------
__global__ void softmax_kernel(const float* __restrict__ partials, float* __restrict__ out) {
  __shared__ float logit[S_];
  __shared__ float wred[2][4];
  int b = blockIdx.x, tid = threadIdx.x;
  int lane = tid & 63, wid = tid >> 6;
  float lmax = -1e30f;
  for (int i = tid; i < S_; i += 256) {
    float acc = 0.f;
#pragma unroll
    for (int d = 0; d < 4; ++d) acc += partials[(size_t)(d * B_ + b) * S_ + i];
    logit[i] = acc;
    lmax = fmaxf(lmax, acc);
  }
#pragma unroll
  for (int o = 32; o; o >>= 1) lmax = fmaxf(lmax, __shfl_xor(lmax, o));
  if (lane == 0) wred[0][wid] = lmax;
  __syncthreads();
  float m = fmaxf(fmaxf(wred[0][0], wred[0][1]), fmaxf(wred[0][2], wred[0][3]));
  float lsum = 0.f;
  for (int i = tid; i < S_; i += 256) {
    float ex = __expf(logit[i] - m);
    logit[i] = ex;
    lsum += ex;
  }
#pragma unroll
  for (int o = 32; o; o >>= 1) lsum += __shfl_xor(lsum, o);
  if (lane == 0) wred[1][wid] = lsum;
  __syncthreads();
  float tot = wred[1][0] + wred[1][1] + wred[1][2] + wred[1][3];
  float inv = 1.0f / tot;
  for (int i = tid; i < S_; i += 256) out[(size_t)b * S_ + i] = logit[i] * inv;
}

extern "C" void kernel_launch(void* const* d_in, const int* in_sizes, int n_in,
                              void* d_out, int out_size, void* d_ws, size_t ws_size,
                              hipStream_t stream) {
  const float* q = (const float*)d_in[0];
  const float* k = (const float*)d_in[1];
  const float* v = (const float*)d_in[2];
  const float* W = (const float*)d_in[3];
  const float* U = (const float*)d_in[4];

  // ws layout: 2x f16[1024*1024] (4 MB) + partials f32[4][32][2048] (1 MB)
  _Float16* wf = (_Float16*)d_ws;
  _Float16* uf = wf + (size_t)D_ * D_;
  float* partials = (float*)(uf + (size_t)D_ * D_);

  prep_kernel<<<dim3(512, 2), 256, 0, stream>>>(W, U, wf, uf);
  gemm_kernel<<<dim3(1024), 512, 0, stream>>>(k, q, v, wf, uf, partials);
  softmax_kernel<<<dim3(B_), 256, 0, stream>>>(partials, (float*)d_out);
}